// Round 10
// baseline (469.485 us; speedup 1.0000x reference)
//
#include <hip/hip_runtime.h>

// Child-Sum Tree-LSTM, 16 trees x branch4 x depth8, HIDDEN=IN_DIM=128.
// R10: R8 structure (leaf 64/block 8-wave; internal 32/block 4-wave) +
//      sibling-tiled c layout: c_tiled[(n>>2)*512 + col*4 + (n&3)] ->
//      combine reads 4 siblings as one float4; epilogues write c as float4.

#define HID 128

typedef unsigned short u16;
typedef __attribute__((ext_vector_type(8))) short short8;
typedef __attribute__((ext_vector_type(4))) float floatx4;

__device__ __forceinline__ float bf2f(u16 u) {
  union { unsigned int u; float f; } v; v.u = ((unsigned int)u) << 16; return v.f;
}
__device__ __forceinline__ u16 f2bf(float f) {
  union { float f; unsigned int u; } v; v.f = f;
  unsigned int r = v.u + 0x7FFFu + ((v.u >> 16) & 1u);
  return (u16)(r >> 16);
}
__device__ __forceinline__ short8 f2bf8(float4 f0, float4 f1) {
  short8 s;
  s[0] = (short)f2bf(f0.x); s[1] = (short)f2bf(f0.y);
  s[2] = (short)f2bf(f0.z); s[3] = (short)f2bf(f0.w);
  s[4] = (short)f2bf(f1.x); s[5] = (short)f2bf(f1.y);
  s[6] = (short)f2bf(f1.z); s[7] = (short)f2bf(f1.w);
  return s;
}
__device__ __forceinline__ float sigm(float x) {
  return __builtin_amdgcn_rcpf(1.0f + __expf(-x));
}
__device__ __forceinline__ float tanh_fast(float x) {
  float ax = fabsf(x);
  float e = __expf(2.0f * ax);
  float t = 1.0f - 2.0f * __builtin_amdgcn_rcpf(e + 1.0f);
  return copysignf(t, x);
}

__global__ void prep_weights(const float* __restrict__ Wix, const float* __restrict__ Wih,
                             const float* __restrict__ Wfx, const float* __restrict__ Wfh,
                             const float* __restrict__ Wox, const float* __restrict__ Woh,
                             const float* __restrict__ Wux, const float* __restrict__ Wuh,
                             u16* __restrict__ Wcat, u16* __restrict__ Wfxb, u16* __restrict__ Wfhb)
{
  int t = blockIdx.x * 256 + threadIdx.x;
  if (t < 98304) {                 // Wcat: 384 rows x 256 k
    int nrow = t >> 8, k = t & 255;
    int gate = nrow >> 7, r = nrow & 127;
    float v;
    if (k < 128) {
      const float* W = (gate == 0) ? Wix : (gate == 1) ? Wox : Wux;
      v = W[r * 128 + k];
    } else {
      const float* W = (gate == 0) ? Wih : (gate == 1) ? Woh : Wuh;
      v = W[r * 128 + (k - 128)];
    }
    Wcat[t] = f2bf(v);
  } else if (t < 98304 + 16384) {
    int i = t - 98304;
    Wfxb[i] = f2bf(Wfx[i]);
  } else if (t < 98304 + 32768) {
    int i = t - 98304 - 16384;
    Wfhb[i] = f2bf(Wfh[i]);
  }
}

// ---------------- Leaf kernel: M=64/block, 8 waves ----------------
__global__ __launch_bounds__(512, 2)
void leaf_kernel(const float* __restrict__ embeds,
                 const u16* __restrict__ Wcat,
                 const float* __restrict__ bix, const float* __restrict__ box,
                 const float* __restrict__ bux,
                 u16* __restrict__ h_all, float* __restrict__ c_tiled,
                 int node_off)
{
  __shared__ char smem[16384];           // 64 rows x 256 B (bf16), XOR-swizzled
  u16* sx = (u16*)smem;

  const int tid  = threadIdx.x;
  const int wave = tid >> 6;             // 0..7
  const int lane = tid & 63;
  const int lg   = lane >> 4;
  const int ln   = lane & 15;
  const int pbase = blockIdx.x * 64;

  {
    int row = tid >> 3;
    int k0  = (tid & 7) * 16;            // float index
    const float* src = embeds + (size_t)(node_off + pbase + row) * HID + k0;
    unsigned sw = ((unsigned)(row & 7)) << 4;
    char* dst = (char*)sx + row * 256;
    float4 f0 = *(const float4*)src;
    float4 f1 = *(const float4*)(src + 4);
    float4 f2 = *(const float4*)(src + 8);
    float4 f3 = *(const float4*)(src + 12);
    *(short8*)(dst + (((unsigned)(k0 * 2)) ^ sw))      = f2bf8(f0, f1);
    *(short8*)(dst + (((unsigned)(k0 * 2 + 16)) ^ sw)) = f2bf8(f2, f3);
  }

  const int col = wave * 16 + ln;
  const float bi = bix[col], bo = box[col], bu = bux[col];

  __syncthreads();

  floatx4 acc[4][3] = {};
#pragma unroll
  for (int kt = 0; kt < 4; ++kt) {
    short8 a[4];
#pragma unroll
    for (int m = 0; m < 4; ++m) {
      int row = m * 16 + ln;
      unsigned sw = ((unsigned)(row & 7)) << 4;
      a[m] = *(const short8*)((char*)sx + row * 256 +
                              (((unsigned)((kt * 32 + lg * 8) * 2)) ^ sw));
    }
#pragma unroll
    for (int g = 0; g < 3; ++g) {
      int NT = g * 8 + wave;
      short8 b = *(const short8*)(Wcat + (size_t)(NT * 16 + ln) * 256 + kt * 32 + lg * 8);
#pragma unroll
      for (int m = 0; m < 4; ++m)
        acc[m][g] = __builtin_amdgcn_mfma_f32_16x16x32_bf16(a[m], b, acc[m][g], 0, 0, 0);
    }
  }

  // epilogue: c -> tiled float4 (4 siblings per lane), h scalar
#pragma unroll
  for (int m = 0; m < 4; ++m) {
    floatx4 c4;
#pragma unroll
    for (int r = 0; r < 4; ++r) {
      int row = m * 16 + lg * 4 + r;
      float iv = sigm(acc[m][0][r] + bi);
      float ov = sigm(acc[m][1][r] + bo);
      float uv = tanh_fast(acc[m][2][r] + bu);
      float cv = iv * uv;
      float hv = ov * tanh_fast(cv);
      c4[r] = cv;
      h_all[(size_t)(node_off + pbase + row) * HID + col] = f2bf(hv);
    }
    size_t tp = (size_t)((node_off + pbase) >> 2) + m * 4 + lg;
    *(floatx4*)(c_tiled + tp * 512 + col * 4) = c4;
  }
}

// ---------------- Internal kernel: 32 parents/block, 4 waves (R8) ----------------
__global__ __launch_bounds__(256, 2)
void level_kernel(const float* __restrict__ embeds,
                  const u16* __restrict__ Wcat,
                  const u16* __restrict__ Wfxb,
                  const u16* __restrict__ Wfhb,
                  const float* __restrict__ bix, const float* __restrict__ bfx,
                  const float* __restrict__ box, const float* __restrict__ bux,
                  u16* __restrict__ h_all, float* __restrict__ c_tiled,
                  int n, int node_off, int child_off)
{
  extern __shared__ char smem[];
  u16*   s_hsum = (u16*)smem;                    // 32x128 bf16, XOR-swizzled (8 KB)
  float* s_fx   = (float*)(smem + 8192);         // 32x128 f32 (16 KB)
  float* s_fc   = (float*)(smem + 8192 + 16384); // 32x128 f32 (16 KB)

  const int tid  = threadIdx.x;
  const int wave = tid >> 6;
  const int lane = tid & 63;
  const int lg   = lane >> 4;
  const int ln   = lane & 15;
  const int pbase = blockIdx.x * 32;

  short8 a_x[2][4];
  {
    const float* xb = embeds + (size_t)(node_off + pbase) * HID;
#pragma unroll
    for (int m = 0; m < 2; ++m)
#pragma unroll
      for (int kt = 0; kt < 4; ++kt) {
        const float* p = xb + (size_t)(m * 16 + ln) * HID + kt * 32 + lg * 8;
        float4 f0 = *(const float4*)p;
        float4 f1 = *(const float4*)(p + 4);
        a_x[m][kt] = f2bf8(f0, f1);
      }
  }

  // ---- fx GEMM ----
  floatx4 acc_fx[2][2] = {};
#pragma unroll
  for (int kt = 0; kt < 4; ++kt)
#pragma unroll
    for (int ntl = 0; ntl < 2; ++ntl) {
      int nt = wave * 2 + ntl;
      short8 b = *(const short8*)(Wfxb + (size_t)(nt * 16 + ln) * HID + kt * 32 + lg * 8);
#pragma unroll
      for (int m = 0; m < 2; ++m)
        acc_fx[m][ntl] = __builtin_amdgcn_mfma_f32_16x16x32_bf16(a_x[m][kt], b, acc_fx[m][ntl], 0, 0, 0);
    }
#pragma unroll
  for (int m = 0; m < 2; ++m)
#pragma unroll
    for (int ntl = 0; ntl < 2; ++ntl) {
      int col = (wave * 2 + ntl) * 16 + ln;
#pragma unroll
      for (int r = 0; r < 4; ++r) {
        int row = m * 16 + lg * 4 + r;
        s_fx[row * HID + col] = acc_fx[m][ntl][r];
      }
    }

  // ---- h_sum ----
  {
    int p = tid >> 3, cg = tid & 7;
    const u16* ch = h_all + (size_t)(child_off + 4 * (pbase + p)) * HID + cg * 16;
    float hs[16];
#pragma unroll
    for (int j = 0; j < 16; ++j) hs[j] = 0.f;
#pragma unroll
    for (int b = 0; b < 4; ++b) {
      short8 v0 = *(const short8*)(ch + (size_t)b * HID);
      short8 v1 = *(const short8*)(ch + (size_t)b * HID + 8);
#pragma unroll
      for (int j = 0; j < 8; ++j) {
        hs[j]     += bf2f((u16)v0[j]);
        hs[8 + j] += bf2f((u16)v1[j]);
      }
    }
    short8 o0, o1;
#pragma unroll
    for (int j = 0; j < 8; ++j) { o0[j] = (short)f2bf(hs[j]); o1[j] = (short)f2bf(hs[8 + j]); }
    unsigned sw = ((unsigned)(p & 7)) << 4;
    *(short8*)((char*)s_hsum + p * 256 + ((cg * 32) ^ sw))      = o0;
    *(short8*)((char*)s_hsum + p * 256 + ((cg * 32 + 16) ^ sw)) = o1;
  }

  // ---- fh GEMM: wave owns child rows [w*32, w*32+32), all 128 cols ----
  short8 a_h[2][4];
  {
    const u16* chb = h_all + (size_t)(child_off + 4 * pbase + wave * 32) * HID;
#pragma unroll
    for (int m = 0; m < 2; ++m)
#pragma unroll
      for (int kt = 0; kt < 4; ++kt)
        a_h[m][kt] = *(const short8*)(chb + (size_t)(m * 16 + ln) * HID + kt * 32 + lg * 8);
  }
  floatx4 acc_fh[2][8] = {};
#pragma unroll
  for (int kt = 0; kt < 4; ++kt)
#pragma unroll
    for (int nt = 0; nt < 8; ++nt) {
      short8 b = *(const short8*)(Wfhb + (size_t)(nt * 16 + ln) * HID + kt * 32 + lg * 8);
#pragma unroll
      for (int m = 0; m < 2; ++m)
        acc_fh[m][nt] = __builtin_amdgcn_mfma_f32_16x16x32_bf16(a_h[m][kt], b, acc_fh[m][nt], 0, 0, 0);
    }

  __syncthreads();

  // ---- f = sigm(fx+bfx+fh); fc via tiled-c float4 (4 siblings per lane) ----
#pragma unroll
  for (int m = 0; m < 2; ++m) {
    int ploc = wave * 8 + m * 4 + lg;
    size_t tslot = (size_t)((child_off >> 2) + pbase) + ploc;   // sibling-group slot
#pragma unroll
    for (int nt = 0; nt < 8; ++nt) {
      int col = nt * 16 + ln;
      float fxv = s_fx[ploc * HID + col] + bfx[col];
      floatx4 cc = *(const floatx4*)(c_tiled + tslot * 512 + col * 4);
      float fc = 0.f;
#pragma unroll
      for (int r = 0; r < 4; ++r)
        fc += sigm(fxv + acc_fh[m][nt][r]) * cc[r];
      s_fc[ploc * HID + col] = fc;
    }
  }
  __syncthreads();

  // ---- main GEMM: K=256 ----
  floatx4 acc[2][3][2] = {};
#pragma unroll
  for (int kt = 0; kt < 8; ++kt) {
    short8 a[2];
    if (kt < 4) {
      a[0] = a_x[0][kt]; a[1] = a_x[1][kt];
    } else {
#pragma unroll
      for (int m = 0; m < 2; ++m) {
        int row = m * 16 + ln;
        unsigned sw = ((unsigned)(row & 7)) << 4;
        int kbyte = ((kt - 4) * 32 + lg * 8) * 2;
        a[m] = *(const short8*)((char*)s_hsum + row * 256 + (kbyte ^ sw));
      }
    }
#pragma unroll
    for (int g = 0; g < 3; ++g)
#pragma unroll
      for (int ntl = 0; ntl < 2; ++ntl) {
        int NT = g * 8 + wave * 2 + ntl;
        short8 b = *(const short8*)(Wcat + (size_t)(NT * 16 + ln) * 256 + kt * 32 + lg * 8);
#pragma unroll
        for (int m = 0; m < 2; ++m)
          acc[m][g][ntl] = __builtin_amdgcn_mfma_f32_16x16x32_bf16(a[m], b, acc[m][g][ntl], 0, 0, 0);
      }
  }

  // ---- epilogue: c -> tiled float4, h scalar ----
#pragma unroll
  for (int m = 0; m < 2; ++m)
#pragma unroll
    for (int ntl = 0; ntl < 2; ++ntl) {
      int col = wave * 32 + ntl * 16 + ln;
      float bi = bix[col], bo = box[col], bu = bux[col];
      if (pbase + m * 16 + lg * 4 < n) {       // sibling group fully valid (n % 16 == 0)
        floatx4 c4;
#pragma unroll
        for (int r = 0; r < 4; ++r) {
          int row = m * 16 + lg * 4 + r;
          float iv = sigm(acc[m][0][ntl][r] + bi);
          float ov = sigm(acc[m][1][ntl][r] + bo);
          float uv = tanh_fast(acc[m][2][ntl][r] + bu);
          float fc = s_fc[row * HID + col];
          float cv = iv * uv + fc;
          float hv = ov * tanh_fast(cv);
          c4[r] = cv;
          h_all[(size_t)(node_off + pbase + row) * HID + col] = f2bf(hv);
        }
        size_t tp = (size_t)((node_off + pbase) >> 2) + m * 4 + lg;
        *(floatx4*)(c_tiled + tp * 512 + col * 4) = c4;
      }
    }
}

__global__ void out_kernel(const u16* __restrict__ h_all, const float* __restrict__ Wout,
                           const float* __restrict__ bout, float* __restrict__ out)
{
  int t = threadIdx.x;
  if (t < 80) {                 // 16 roots x 5 labels
    int row = t / 5, lbl = t - row * 5;
    float s = bout[lbl];
    for (int k = 0; k < 128; ++k)
      s += bf2f(h_all[row * 128 + k]) * Wout[lbl * 128 + k];
    out[t] = s;
  }
}

extern "C" void kernel_launch(void* const* d_in, const int* in_sizes, int n_in,
                              void* d_out, int out_size, void* d_ws, size_t ws_size,
                              hipStream_t stream)
{
  const float* embeds = (const float*)d_in[0];
  const float* Wix = (const float*)d_in[1];
  const float* bix = (const float*)d_in[2];
  const float* Wih = (const float*)d_in[3];
  const float* Wfx = (const float*)d_in[4];
  const float* bfx = (const float*)d_in[5];
  const float* Wfh = (const float*)d_in[6];
  const float* Wox = (const float*)d_in[7];
  const float* box = (const float*)d_in[8];
  const float* Woh = (const float*)d_in[9];
  const float* Wux = (const float*)d_in[10];
  const float* bux = (const float*)d_in[11];
  const float* Wuh = (const float*)d_in[12];
  const float* Wout = (const float*)d_in[13];
  const float* bout = (const float*)d_in[14];

  static const int counts[8]  = {16, 64, 256, 1024, 4096, 16384, 65536, 262144};
  static const int offsets[9] = {0, 16, 80, 336, 1360, 5456, 21840, 87376, 349520};

  char* ws = (char*)d_ws;
  u16*   h_all   = (u16*)ws;                                 // 89,477,120 B
  float* c_tiled = (float*)(ws + 89477120);                  // 87380*512*4 = 178,954,240 B
  u16*   Wcat  = (u16*)(ws + 89477120 + 178954240);          // 384*256*2
  u16*   Wfxb  = Wcat + 384 * 256;
  u16*   Wfhb  = Wfxb + 128 * 128;

  prep_weights<<<512, 256, 0, stream>>>(Wix, Wih, Wfx, Wfh, Wox, Woh, Wux, Wuh,
                                        Wcat, Wfxb, Wfhb);

  // level 7 (leaves): M=64/block, 8 waves
  leaf_kernel<<<262144 / 64, 512, 0, stream>>>(
      embeds, Wcat, bix, box, bux, h_all, c_tiled, 87376);

  // levels 6..0 (internal): 32 parents/block
  for (int l = 6; l >= 0; --l) {
    int n = counts[l];
    int grid = (n + 31) / 32;
    level_kernel<<<grid, 256, 40960, stream>>>(
        embeds, Wcat, Wfxb, Wfhb, bix, bfx, box, bux,
        h_all, c_tiled, n, offsets[l], offsets[l + 1]);
  }

  out_kernel<<<1, 128, 0, stream>>>(h_all, Wout, bout, (float*)d_out);
}

// Round 11
// 329.259 us; speedup vs baseline: 1.4259x; 1.4259x over previous
//
#include <hip/hip_runtime.h>

// Child-Sum Tree-LSTM, 16 trees x branch4 x depth8, HIDDEN=IN_DIM=128.
// R11: producer-consumer fusion. Each level kernel computes h,c for its 64
//      nodes AND produces for the parent level: hsum (in-lane sibling add)
//      and fh = Wfh@h (16-MFMA GEMM on the LDS-resident h tile).
//      Parent kernel: stage x + stage hsum -> fx GEMM -> combine (loads
//      child fh + c) -> main GEMM -> epilogue. No h_sum reduce, no fh GEMM,
//      no 64-AGPR accumulator in the consumer.
//      hf buffer slot-shares per node: hsum(p) [written by child level,
//      read by p's level] then fh(p) [written by p's level epilogue, read
//      by p's parent]. Root slots hold final root h for out_kernel.

#define HID 128

typedef unsigned short u16;
typedef __attribute__((ext_vector_type(8))) short short8;
typedef __attribute__((ext_vector_type(4))) float floatx4;

__device__ __forceinline__ float bf2f(u16 u) {
  union { unsigned int u; float f; } v; v.u = ((unsigned int)u) << 16; return v.f;
}
__device__ __forceinline__ u16 f2bf(float f) {
  union { float f; unsigned int u; } v; v.f = f;
  unsigned int r = v.u + 0x7FFFu + ((v.u >> 16) & 1u);
  return (u16)(r >> 16);
}
__device__ __forceinline__ short8 f2bf8(float4 f0, float4 f1) {
  short8 s;
  s[0] = (short)f2bf(f0.x); s[1] = (short)f2bf(f0.y);
  s[2] = (short)f2bf(f0.z); s[3] = (short)f2bf(f0.w);
  s[4] = (short)f2bf(f1.x); s[5] = (short)f2bf(f1.y);
  s[6] = (short)f2bf(f1.z); s[7] = (short)f2bf(f1.w);
  return s;
}
__device__ __forceinline__ float sigm(float x) {
  return __builtin_amdgcn_rcpf(1.0f + __expf(-x));
}
__device__ __forceinline__ float tanh_fast(float x) {
  float ax = fabsf(x);
  float e = __expf(2.0f * ax);
  float t = 1.0f - 2.0f * __builtin_amdgcn_rcpf(e + 1.0f);
  return copysignf(t, x);
}

__global__ void prep_weights(const float* __restrict__ Wix, const float* __restrict__ Wih,
                             const float* __restrict__ Wfx, const float* __restrict__ Wfh,
                             const float* __restrict__ Wox, const float* __restrict__ Woh,
                             const float* __restrict__ Wux, const float* __restrict__ Wuh,
                             u16* __restrict__ Wcat, u16* __restrict__ Wfxb, u16* __restrict__ Wfhb)
{
  int t = blockIdx.x * 256 + threadIdx.x;
  if (t < 98304) {                 // Wcat: 384 rows x 256 k
    int nrow = t >> 8, k = t & 255;
    int gate = nrow >> 7, r = nrow & 127;
    float v;
    if (k < 128) {
      const float* W = (gate == 0) ? Wix : (gate == 1) ? Wox : Wux;
      v = W[r * 128 + k];
    } else {
      const float* W = (gate == 0) ? Wih : (gate == 1) ? Woh : Wuh;
      v = W[r * 128 + (k - 128)];
    }
    Wcat[t] = f2bf(v);
  } else if (t < 98304 + 16384) {
    int i = t - 98304;
    Wfxb[i] = f2bf(Wfx[i]);
  } else if (t < 98304 + 32768) {
    int i = t - 98304 - 16384;
    Wfhb[i] = f2bf(Wfh[i]);
  }
}

// MODE: 0 = leaf (no children), 1 = internal, 2 = root (no fh/hsum output)
// 64 nodes/block, 512 threads (8 waves). Wave w owns within-gate cols
// [16w, 16w+16) in every phase. LDS: sx 16KB (+ shs 16KB if MODE>=1).
template <int MODE>
__global__ __launch_bounds__(512, 2)
void tree_kernel(const float* __restrict__ embeds,
                 const u16* __restrict__ Wcat,
                 const u16* __restrict__ Wfxb,
                 const u16* __restrict__ Wfhb,
                 const float* __restrict__ bix, const float* __restrict__ bfx,
                 const float* __restrict__ box, const float* __restrict__ bux,
                 u16* __restrict__ hf, float* __restrict__ c_buf,
                 int n, int noff, int coff, int poff)
{
  constexpr bool HASC = (MODE >= 1);
  constexpr bool ROOT = (MODE == 2);
  extern __shared__ char smem[];
  u16* sx  = (u16*)smem;                    // 64 x 256B, swz bf16 (x, later h)
  u16* shs = (u16*)(smem + 16384);          // 64 x 256B, swz bf16 (hsum)

  const int tid  = threadIdx.x;
  const int wave = tid >> 6;                // 0..7
  const int lane = tid & 63;
  const int lg   = lane >> 4;
  const int ln   = lane & 15;
  const int pbase = blockIdx.x * 64;
  const int col  = wave * 16 + ln;

  // ---- stage x: thread t -> row t>>3, 16-float chunk t&7 ----
  {
    int row = tid >> 3;
    int k0  = (tid & 7) * 16;
    const float* src = embeds + (size_t)(noff + pbase + row) * HID + k0;
    unsigned sw = ((unsigned)(row & 7)) << 4;
    char* dst = (char*)sx + row * 256;
    float4 f0 = *(const float4*)src;
    float4 f1 = *(const float4*)(src + 4);
    float4 f2 = *(const float4*)(src + 8);
    float4 f3 = *(const float4*)(src + 12);
    *(short8*)(dst + (((unsigned)(k0 * 2)) ^ sw))      = f2bf8(f0, f1);
    *(short8*)(dst + (((unsigned)(k0 * 2 + 16)) ^ sw)) = f2bf8(f2, f3);
  }

  // ---- stage hsum (direct copy; produced by child level) ----
  if constexpr (HASC) {
    int row = tid >> 3, cg = tid & 7;
    const u16* src = hf + (size_t)(noff + pbase + row) * HID + cg * 16;
    short8 v0 = *(const short8*)src;
    short8 v1 = *(const short8*)(src + 8);
    unsigned sw = ((unsigned)(row & 7)) << 4;
    char* dst = (char*)shs + row * 256;
    *(short8*)(dst + ((cg * 32) ^ sw))      = v0;
    *(short8*)(dst + ((cg * 32 + 16) ^ sw)) = v1;
  }

  __syncthreads();

  // ---- fx GEMM + combine (fc) ----
  float fc[4][4];
  if constexpr (HASC) {
    floatx4 accx[4] = {};
#pragma unroll
    for (int kt = 0; kt < 4; ++kt) {
      short8 b = *(const short8*)(Wfxb + (size_t)(wave * 16 + ln) * HID + kt * 32 + lg * 8);
#pragma unroll
      for (int m = 0; m < 4; ++m) {
        int row = m * 16 + ln;
        unsigned sw = ((unsigned)(row & 7)) << 4;
        short8 a = *(const short8*)((char*)sx + row * 256 +
                                    (((unsigned)((kt * 32 + lg * 8) * 2)) ^ sw));
        accx[m] = __builtin_amdgcn_mfma_f32_16x16x32_bf16(a, b, accx[m], 0, 0, 0);
      }
    }
    // combine: per parent row, read 4 children's fh (bf16) + c (f32)
    float bf = bfx[col];
#pragma unroll
    for (int m = 0; m < 4; ++m)
#pragma unroll
      for (int r = 0; r < 4; ++r) {
        int row = m * 16 + lg * 4 + r;
        size_t cb = (size_t)(coff + 4 * (pbase + row)) * HID + col;
        float fxv = accx[m][r] + bf;
        float f0 = sigm(fxv + bf2f(hf[cb]));
        float f1 = sigm(fxv + bf2f(hf[cb + HID]));
        float f2 = sigm(fxv + bf2f(hf[cb + 2 * HID]));
        float f3 = sigm(fxv + bf2f(hf[cb + 3 * HID]));
        fc[m][r] = f0 * c_buf[cb] + f1 * c_buf[cb + HID] +
                   f2 * c_buf[cb + 2 * HID] + f3 * c_buf[cb + 3 * HID];
      }
  }

  // ---- main GEMM: [x | hsum] @ Wcat^T, K = 256 (internal/root) / 128 (leaf) ----
  floatx4 acc[4][3] = {};
  constexpr int KT = HASC ? 8 : 4;
#pragma unroll
  for (int kt = 0; kt < KT; ++kt) {
    short8 a[4];
#pragma unroll
    for (int m = 0; m < 4; ++m) {
      int row = m * 16 + ln;
      unsigned sw = ((unsigned)(row & 7)) << 4;
      const char* base = (kt < 4) ? (const char*)sx : (const char*)shs;
      int kb = ((kt & 3) * 32 + lg * 8) * 2;
      a[m] = *(const short8*)(base + row * 256 + (((unsigned)kb) ^ sw));
    }
#pragma unroll
    for (int g = 0; g < 3; ++g) {
      short8 b = *(const short8*)(Wcat + (size_t)((g * 8 + wave) * 16 + ln) * 256 + kt * 32 + lg * 8);
#pragma unroll
      for (int m = 0; m < 4; ++m)
        acc[m][g] = __builtin_amdgcn_mfma_f32_16x16x32_bf16(a[m], b, acc[m][g], 0, 0, 0);
    }
  }

  __syncthreads();   // sx reads done (h will overwrite it); hsum reads long done

  // ---- epilogue: c,h; h -> LDS for fh GEMM; in-lane hsum for parent ----
  {
    float bi = bix[col], bo = box[col], bu = bux[col];
#pragma unroll
    for (int m = 0; m < 4; ++m) {
      float hs4 = 0.f;
#pragma unroll
      for (int r = 0; r < 4; ++r) {
        int row = m * 16 + lg * 4 + r;
        bool ok = ROOT ? (pbase + row < n) : true;
        if (ok) {
          float iv = sigm(acc[m][0][r] + bi);
          float ov = sigm(acc[m][1][r] + bo);
          float uv = tanh_fast(acc[m][2][r] + bu);
          float fcv = HASC ? fc[m][r] : 0.f;
          float cv = iv * uv + fcv;
          float hv = ov * tanh_fast(cv);
          c_buf[(size_t)(noff + pbase + row) * HID + col] = cv;
          if constexpr (ROOT) {
            hf[(size_t)(noff + pbase + row) * HID + col] = f2bf(hv);
          } else {
            hs4 += hv;
            unsigned sw = ((unsigned)(row & 7)) << 4;
            *(u16*)((char*)sx + row * 256 + (((unsigned)(col * 2)) ^ sw)) = f2bf(hv);
          }
        }
      }
      if constexpr (!ROOT)
        hf[(size_t)(poff + (pbase >> 2) + m * 4 + lg) * HID + col] = f2bf(hs4);
    }
  }

  // ---- fh GEMM: fh = Wfh @ h (A = h tile in LDS), write for parent ----
  if constexpr (!ROOT) {
    __syncthreads();   // all h writes to sx visible
    floatx4 ah[4] = {};
#pragma unroll
    for (int kt = 0; kt < 4; ++kt) {
      short8 b = *(const short8*)(Wfhb + (size_t)(wave * 16 + ln) * HID + kt * 32 + lg * 8);
#pragma unroll
      for (int m = 0; m < 4; ++m) {
        int row = m * 16 + ln;
        unsigned sw = ((unsigned)(row & 7)) << 4;
        short8 a = *(const short8*)((char*)sx + row * 256 +
                                    (((unsigned)((kt * 32 + lg * 8) * 2)) ^ sw));
        ah[m] = __builtin_amdgcn_mfma_f32_16x16x32_bf16(a, b, ah[m], 0, 0, 0);
      }
    }
#pragma unroll
    for (int m = 0; m < 4; ++m)
#pragma unroll
      for (int r = 0; r < 4; ++r) {
        int row = m * 16 + lg * 4 + r;
        hf[(size_t)(noff + pbase + row) * HID + col] = f2bf(ah[m][r]);
      }
  }
}

__global__ void out_kernel(const u16* __restrict__ hf, const float* __restrict__ Wout,
                           const float* __restrict__ bout, float* __restrict__ out)
{
  int t = threadIdx.x;
  if (t < 80) {                 // 16 roots x 5 labels
    int row = t / 5, lbl = t - row * 5;
    float s = bout[lbl];
    for (int k = 0; k < 128; ++k)
      s += bf2f(hf[row * 128 + k]) * Wout[lbl * 128 + k];
    out[t] = s;
  }
}

extern "C" void kernel_launch(void* const* d_in, const int* in_sizes, int n_in,
                              void* d_out, int out_size, void* d_ws, size_t ws_size,
                              hipStream_t stream)
{
  const float* embeds = (const float*)d_in[0];
  const float* Wix = (const float*)d_in[1];
  const float* bix = (const float*)d_in[2];
  const float* Wih = (const float*)d_in[3];
  const float* Wfx = (const float*)d_in[4];
  const float* bfx = (const float*)d_in[5];
  const float* Wfh = (const float*)d_in[6];
  const float* Wox = (const float*)d_in[7];
  const float* box = (const float*)d_in[8];
  const float* Woh = (const float*)d_in[9];
  const float* Wux = (const float*)d_in[10];
  const float* bux = (const float*)d_in[11];
  const float* Wuh = (const float*)d_in[12];
  const float* Wout = (const float*)d_in[13];
  const float* bout = (const float*)d_in[14];

  static const int counts[8]  = {16, 64, 256, 1024, 4096, 16384, 65536, 262144};
  static const int offsets[9] = {0, 16, 80, 336, 1360, 5456, 21840, 87376, 349520};

  char* ws = (char*)d_ws;
  u16*   hf    = (u16*)ws;                                   // 89,477,120 B
  float* c_buf = (float*)(ws + 89477120);                    // 178,954,240 B
  u16*   Wcat  = (u16*)(ws + 89477120 + 178954240);          // 384*256*2
  u16*   Wfxb  = Wcat + 384 * 256;
  u16*   Wfhb  = Wfxb + 128 * 128;

  prep_weights<<<512, 256, 0, stream>>>(Wix, Wih, Wfx, Wfh, Wox, Woh, Wux, Wuh,
                                        Wcat, Wfxb, Wfhb);

  // level 7 (leaves): produces c, fh, hsum(level-6 parents)
  tree_kernel<0><<<262144 / 64, 512, 16384, stream>>>(
      embeds, Wcat, Wfxb, Wfhb, bix, bfx, box, bux,
      hf, c_buf, 262144, 87376, 0, 21840);

  // levels 6..1 (internal)
  for (int l = 6; l >= 1; --l) {
    int n = counts[l];
    tree_kernel<1><<<n / 64, 512, 32768, stream>>>(
        embeds, Wcat, Wfxb, Wfhb, bix, bfx, box, bux,
        hf, c_buf, n, offsets[l], offsets[l + 1], offsets[l - 1]);
  }

  // level 0 (roots): writes root h into hf slots 0..15
  tree_kernel<2><<<1, 512, 32768, stream>>>(
      embeds, Wcat, Wfxb, Wfhb, bix, bfx, box, bux,
      hf, c_buf, 16, 0, 16, 0);

  out_kernel<<<1, 128, 0, stream>>>(hf, Wout, bout, (float*)d_out);
}

// Round 12
// 328.130 us; speedup vs baseline: 1.4308x; 1.0034x over previous
//
#include <hip/hip_runtime.h>
#include <hip/hip_bf16.h>

// Child-Sum Tree-LSTM, 16 trees x branch4 x depth8, HIDDEN=IN_DIM=128.
// R12 = R11 (producer-consumer fusion: child level computes hsum + fh) +
//   (a) native bf16 converts (__float2bfloat16 -> v_cvt_pk_bf16_f32) replacing
//       manual-RNE bit tricks (same rounding, ~8x fewer VALU ops), and
//   (b) combine phase batches its 32 child c/fh loads per m-group into
//       explicit register arrays before the gate math (MLP 1 -> 32).

#define HID 128

typedef unsigned short u16;
typedef __attribute__((ext_vector_type(8))) short short8;
typedef __attribute__((ext_vector_type(4))) float floatx4;

__device__ __forceinline__ float bf2f(u16 u) {
  union { unsigned int u; float f; } v; v.u = ((unsigned int)u) << 16; return v.f;
}
__device__ __forceinline__ u16 f2bf(float f) {
  __hip_bfloat16 b = __float2bfloat16(f);           // native RNE cvt on gfx950
  return *reinterpret_cast<u16*>(&b);
}
__device__ __forceinline__ short8 f2bf8(float4 f0, float4 f1) {
  short8 s;
  s[0] = (short)f2bf(f0.x); s[1] = (short)f2bf(f0.y);
  s[2] = (short)f2bf(f0.z); s[3] = (short)f2bf(f0.w);
  s[4] = (short)f2bf(f1.x); s[5] = (short)f2bf(f1.y);
  s[6] = (short)f2bf(f1.z); s[7] = (short)f2bf(f1.w);
  return s;
}
__device__ __forceinline__ float sigm(float x) {
  return __builtin_amdgcn_rcpf(1.0f + __expf(-x));
}
__device__ __forceinline__ float tanh_fast(float x) {
  float ax = fabsf(x);
  float e = __expf(2.0f * ax);
  float t = 1.0f - 2.0f * __builtin_amdgcn_rcpf(e + 1.0f);
  return copysignf(t, x);
}

__global__ void prep_weights(const float* __restrict__ Wix, const float* __restrict__ Wih,
                             const float* __restrict__ Wfx, const float* __restrict__ Wfh,
                             const float* __restrict__ Wox, const float* __restrict__ Woh,
                             const float* __restrict__ Wux, const float* __restrict__ Wuh,
                             u16* __restrict__ Wcat, u16* __restrict__ Wfxb, u16* __restrict__ Wfhb)
{
  int t = blockIdx.x * 256 + threadIdx.x;
  if (t < 98304) {                 // Wcat: 384 rows x 256 k
    int nrow = t >> 8, k = t & 255;
    int gate = nrow >> 7, r = nrow & 127;
    float v;
    if (k < 128) {
      const float* W = (gate == 0) ? Wix : (gate == 1) ? Wox : Wux;
      v = W[r * 128 + k];
    } else {
      const float* W = (gate == 0) ? Wih : (gate == 1) ? Woh : Wuh;
      v = W[r * 128 + (k - 128)];
    }
    Wcat[t] = f2bf(v);
  } else if (t < 98304 + 16384) {
    int i = t - 98304;
    Wfxb[i] = f2bf(Wfx[i]);
  } else if (t < 98304 + 32768) {
    int i = t - 98304 - 16384;
    Wfhb[i] = f2bf(Wfh[i]);
  }
}

// MODE: 0 = leaf (no children), 1 = internal, 2 = root (no fh/hsum output)
// 64 nodes/block, 512 threads (8 waves). Wave w owns within-gate cols
// [16w, 16w+16) in every phase. LDS: sx 16KB (+ shs 16KB if MODE>=1).
template <int MODE>
__global__ __launch_bounds__(512, 2)
void tree_kernel(const float* __restrict__ embeds,
                 const u16* __restrict__ Wcat,
                 const u16* __restrict__ Wfxb,
                 const u16* __restrict__ Wfhb,
                 const float* __restrict__ bix, const float* __restrict__ bfx,
                 const float* __restrict__ box, const float* __restrict__ bux,
                 u16* __restrict__ hf, float* __restrict__ c_buf,
                 int n, int noff, int coff, int poff)
{
  constexpr bool HASC = (MODE >= 1);
  constexpr bool ROOT = (MODE == 2);
  extern __shared__ char smem[];
  u16* sx  = (u16*)smem;                    // 64 x 256B, swz bf16 (x, later h)
  u16* shs = (u16*)(smem + 16384);          // 64 x 256B, swz bf16 (hsum)

  const int tid  = threadIdx.x;
  const int wave = tid >> 6;                // 0..7
  const int lane = tid & 63;
  const int lg   = lane >> 4;
  const int ln   = lane & 15;
  const int pbase = blockIdx.x * 64;
  const int col  = wave * 16 + ln;

  // ---- stage x: thread t -> row t>>3, 16-float chunk t&7 ----
  {
    int row = tid >> 3;
    int k0  = (tid & 7) * 16;
    const float* src = embeds + (size_t)(noff + pbase + row) * HID + k0;
    unsigned sw = ((unsigned)(row & 7)) << 4;
    char* dst = (char*)sx + row * 256;
    float4 f0 = *(const float4*)src;
    float4 f1 = *(const float4*)(src + 4);
    float4 f2 = *(const float4*)(src + 8);
    float4 f3 = *(const float4*)(src + 12);
    *(short8*)(dst + (((unsigned)(k0 * 2)) ^ sw))      = f2bf8(f0, f1);
    *(short8*)(dst + (((unsigned)(k0 * 2 + 16)) ^ sw)) = f2bf8(f2, f3);
  }

  // ---- stage hsum (direct copy; produced by child level) ----
  if constexpr (HASC) {
    int row = tid >> 3, cg = tid & 7;
    const u16* src = hf + (size_t)(noff + pbase + row) * HID + cg * 16;
    short8 v0 = *(const short8*)src;
    short8 v1 = *(const short8*)(src + 8);
    unsigned sw = ((unsigned)(row & 7)) << 4;
    char* dst = (char*)shs + row * 256;
    *(short8*)(dst + ((cg * 32) ^ sw))      = v0;
    *(short8*)(dst + ((cg * 32 + 16) ^ sw)) = v1;
  }

  __syncthreads();

  // ---- fx GEMM + combine (fc) ----
  float fc[4][4];
  if constexpr (HASC) {
    floatx4 accx[4] = {};
#pragma unroll
    for (int kt = 0; kt < 4; ++kt) {
      short8 b = *(const short8*)(Wfxb + (size_t)(wave * 16 + ln) * HID + kt * 32 + lg * 8);
#pragma unroll
      for (int m = 0; m < 4; ++m) {
        int row = m * 16 + ln;
        unsigned sw = ((unsigned)(row & 7)) << 4;
        short8 a = *(const short8*)((char*)sx + row * 256 +
                                    (((unsigned)((kt * 32 + lg * 8) * 2)) ^ sw));
        accx[m] = __builtin_amdgcn_mfma_f32_16x16x32_bf16(a, b, accx[m], 0, 0, 0);
      }
    }
    // combine: batch-load the 16 c (f32) + 16 fh (bf16) per m-group first
    // (32 concurrent loads), THEN do the gate math. MLP fix for the serial
    // per-level latency (R11: loads were interleaved with math, ~1 in flight).
    float bf = bfx[col];
#pragma unroll
    for (int m = 0; m < 4; ++m) {
      float cc[4][4];
      u16   ff[4][4];
#pragma unroll
      for (int r = 0; r < 4; ++r) {
        int row = m * 16 + lg * 4 + r;
        size_t cb = (size_t)(coff + 4 * (pbase + row)) * HID + col;
#pragma unroll
        for (int k = 0; k < 4; ++k) {
          cc[r][k] = c_buf[cb + (size_t)k * HID];
          ff[r][k] = hf[cb + (size_t)k * HID];
        }
      }
#pragma unroll
      for (int r = 0; r < 4; ++r) {
        float fxv = accx[m][r] + bf;
        float s = 0.f;
#pragma unroll
        for (int k = 0; k < 4; ++k)
          s += sigm(fxv + bf2f(ff[r][k])) * cc[r][k];
        fc[m][r] = s;
      }
    }
  }

  // ---- main GEMM: [x | hsum] @ Wcat^T, K = 256 (internal/root) / 128 (leaf) ----
  floatx4 acc[4][3] = {};
  constexpr int KT = HASC ? 8 : 4;
#pragma unroll
  for (int kt = 0; kt < KT; ++kt) {
    short8 a[4];
#pragma unroll
    for (int m = 0; m < 4; ++m) {
      int row = m * 16 + ln;
      unsigned sw = ((unsigned)(row & 7)) << 4;
      const char* base = (kt < 4) ? (const char*)sx : (const char*)shs;
      int kb = ((kt & 3) * 32 + lg * 8) * 2;
      a[m] = *(const short8*)(base + row * 256 + (((unsigned)kb) ^ sw));
    }
#pragma unroll
    for (int g = 0; g < 3; ++g) {
      short8 b = *(const short8*)(Wcat + (size_t)((g * 8 + wave) * 16 + ln) * 256 + kt * 32 + lg * 8);
#pragma unroll
      for (int m = 0; m < 4; ++m)
        acc[m][g] = __builtin_amdgcn_mfma_f32_16x16x32_bf16(a[m], b, acc[m][g], 0, 0, 0);
    }
  }

  __syncthreads();   // sx reads done (h will overwrite it); hsum reads long done

  // ---- epilogue: c,h; h -> LDS for fh GEMM; in-lane hsum for parent ----
  {
    float bi = bix[col], bo = box[col], bu = bux[col];
#pragma unroll
    for (int m = 0; m < 4; ++m) {
      float hs4 = 0.f;
#pragma unroll
      for (int r = 0; r < 4; ++r) {
        int row = m * 16 + lg * 4 + r;
        bool ok = ROOT ? (pbase + row < n) : true;
        if (ok) {
          float iv = sigm(acc[m][0][r] + bi);
          float ov = sigm(acc[m][1][r] + bo);
          float uv = tanh_fast(acc[m][2][r] + bu);
          float fcv = HASC ? fc[m][r] : 0.f;
          float cv = iv * uv + fcv;
          float hv = ov * tanh_fast(cv);
          c_buf[(size_t)(noff + pbase + row) * HID + col] = cv;
          if constexpr (ROOT) {
            hf[(size_t)(noff + pbase + row) * HID + col] = f2bf(hv);
          } else {
            hs4 += hv;
            unsigned sw = ((unsigned)(row & 7)) << 4;
            *(u16*)((char*)sx + row * 256 + (((unsigned)(col * 2)) ^ sw)) = f2bf(hv);
          }
        }
      }
      if constexpr (!ROOT)
        hf[(size_t)(poff + (pbase >> 2) + m * 4 + lg) * HID + col] = f2bf(hs4);
    }
  }

  // ---- fh GEMM: fh = Wfh @ h (A = h tile in LDS), write for parent ----
  if constexpr (!ROOT) {
    __syncthreads();   // all h writes to sx visible
    floatx4 ah[4] = {};
#pragma unroll
    for (int kt = 0; kt < 4; ++kt) {
      short8 b = *(const short8*)(Wfhb + (size_t)(wave * 16 + ln) * HID + kt * 32 + lg * 8);
#pragma unroll
      for (int m = 0; m < 4; ++m) {
        int row = m * 16 + ln;
        unsigned sw = ((unsigned)(row & 7)) << 4;
        short8 a = *(const short8*)((char*)sx + row * 256 +
                                    (((unsigned)((kt * 32 + lg * 8) * 2)) ^ sw));
        ah[m] = __builtin_amdgcn_mfma_f32_16x16x32_bf16(a, b, ah[m], 0, 0, 0);
      }
    }
#pragma unroll
    for (int m = 0; m < 4; ++m)
#pragma unroll
      for (int r = 0; r < 4; ++r) {
        int row = m * 16 + lg * 4 + r;
        hf[(size_t)(noff + pbase + row) * HID + col] = f2bf(ah[m][r]);
      }
  }
}

__global__ void out_kernel(const u16* __restrict__ hf, const float* __restrict__ Wout,
                           const float* __restrict__ bout, float* __restrict__ out)
{
  int t = threadIdx.x;
  if (t < 80) {                 // 16 roots x 5 labels
    int row = t / 5, lbl = t - row * 5;
    float s = bout[lbl];
    for (int k = 0; k < 128; ++k)
      s += bf2f(hf[row * 128 + k]) * Wout[lbl * 128 + k];
    out[t] = s;
  }
}

extern "C" void kernel_launch(void* const* d_in, const int* in_sizes, int n_in,
                              void* d_out, int out_size, void* d_ws, size_t ws_size,
                              hipStream_t stream)
{
  const float* embeds = (const float*)d_in[0];
  const float* Wix = (const float*)d_in[1];
  const float* bix = (const float*)d_in[2];
  const float* Wih = (const float*)d_in[3];
  const float* Wfx = (const float*)d_in[4];
  const float* bfx = (const float*)d_in[5];
  const float* Wfh = (const float*)d_in[6];
  const float* Wox = (const float*)d_in[7];
  const float* box = (const float*)d_in[8];
  const float* Woh = (const float*)d_in[9];
  const float* Wux = (const float*)d_in[10];
  const float* bux = (const float*)d_in[11];
  const float* Wuh = (const float*)d_in[12];
  const float* Wout = (const float*)d_in[13];
  const float* bout = (const float*)d_in[14];

  static const int counts[8]  = {16, 64, 256, 1024, 4096, 16384, 65536, 262144};
  static const int offsets[9] = {0, 16, 80, 336, 1360, 5456, 21840, 87376, 349520};

  char* ws = (char*)d_ws;
  u16*   hf    = (u16*)ws;                                   // 89,477,120 B
  float* c_buf = (float*)(ws + 89477120);                    // 178,954,240 B
  u16*   Wcat  = (u16*)(ws + 89477120 + 178954240);          // 384*256*2
  u16*   Wfxb  = Wcat + 384 * 256;
  u16*   Wfhb  = Wfxb + 128 * 128;

  prep_weights<<<512, 256, 0, stream>>>(Wix, Wih, Wfx, Wfh, Wox, Woh, Wux, Wuh,
                                        Wcat, Wfxb, Wfhb);

  // level 7 (leaves): produces c, fh, hsum(level-6 parents)
  tree_kernel<0><<<262144 / 64, 512, 16384, stream>>>(
      embeds, Wcat, Wfxb, Wfhb, bix, bfx, box, bux,
      hf, c_buf, 262144, 87376, 0, 21840);

  // levels 6..1 (internal)
  for (int l = 6; l >= 1; --l) {
    int n = counts[l];
    tree_kernel<1><<<n / 64, 512, 32768, stream>>>(
        embeds, Wcat, Wfxb, Wfhb, bix, bfx, box, bux,
        hf, c_buf, n, offsets[l], offsets[l + 1], offsets[l - 1]);
  }

  // level 0 (roots): writes root h into hf slots 0..15
  tree_kernel<2><<<1, 512, 32768, stream>>>(
      embeds, Wcat, Wfxb, Wfhb, bix, bfx, box, bux,
      hf, c_buf, 16, 0, 16, 0);

  out_kernel<<<1, 128, 0, stream>>>(hf, Wout, bout, (float*)d_out);
}

// Round 13
// 289.552 us; speedup vs baseline: 1.6214x; 1.1332x over previous
//
#include <hip/hip_runtime.h>
#include <hip/hip_bf16.h>

// Child-Sum Tree-LSTM, 16 trees x branch4 x depth8, HIDDEN=IN_DIM=128.
// R13 = R12 + packed (fh,c) bf16 pairs in one u32 buffer (cf_buf):
//   - producer keeps c in regs through the fh GEMM, writes one u32/elem
//   - combine loads one u32/child-elem (was f32 c + u16 fh)
//   - c stored as bf16 (error damped by tanh saturation + Wout*0.01)

#define HID 128

typedef unsigned short u16;
typedef unsigned int u32;
typedef __attribute__((ext_vector_type(8))) short short8;
typedef __attribute__((ext_vector_type(4))) float floatx4;

__device__ __forceinline__ float bf2f(u16 u) {
  union { unsigned int u; float f; } v; v.u = ((unsigned int)u) << 16; return v.f;
}
__device__ __forceinline__ u16 f2bf(float f) {
  __hip_bfloat16 b = __float2bfloat16(f);           // native RNE cvt on gfx950
  return *reinterpret_cast<u16*>(&b);
}
__device__ __forceinline__ short8 f2bf8(float4 f0, float4 f1) {
  short8 s;
  s[0] = (short)f2bf(f0.x); s[1] = (short)f2bf(f0.y);
  s[2] = (short)f2bf(f0.z); s[3] = (short)f2bf(f0.w);
  s[4] = (short)f2bf(f1.x); s[5] = (short)f2bf(f1.y);
  s[6] = (short)f2bf(f1.z); s[7] = (short)f2bf(f1.w);
  return s;
}
__device__ __forceinline__ float sigm(float x) {
  return __builtin_amdgcn_rcpf(1.0f + __expf(-x));
}
__device__ __forceinline__ float tanh_fast(float x) {
  float ax = fabsf(x);
  float e = __expf(2.0f * ax);
  float t = 1.0f - 2.0f * __builtin_amdgcn_rcpf(e + 1.0f);
  return copysignf(t, x);
}

__global__ void prep_weights(const float* __restrict__ Wix, const float* __restrict__ Wih,
                             const float* __restrict__ Wfx, const float* __restrict__ Wfh,
                             const float* __restrict__ Wox, const float* __restrict__ Woh,
                             const float* __restrict__ Wux, const float* __restrict__ Wuh,
                             u16* __restrict__ Wcat, u16* __restrict__ Wfxb, u16* __restrict__ Wfhb)
{
  int t = blockIdx.x * 256 + threadIdx.x;
  if (t < 98304) {                 // Wcat: 384 rows x 256 k
    int nrow = t >> 8, k = t & 255;
    int gate = nrow >> 7, r = nrow & 127;
    float v;
    if (k < 128) {
      const float* W = (gate == 0) ? Wix : (gate == 1) ? Wox : Wux;
      v = W[r * 128 + k];
    } else {
      const float* W = (gate == 0) ? Wih : (gate == 1) ? Woh : Wuh;
      v = W[r * 128 + (k - 128)];
    }
    Wcat[t] = f2bf(v);
  } else if (t < 98304 + 16384) {
    int i = t - 98304;
    Wfxb[i] = f2bf(Wfx[i]);
  } else if (t < 98304 + 32768) {
    int i = t - 98304 - 16384;
    Wfhb[i] = f2bf(Wfh[i]);
  }
}

// MODE: 0 = leaf (no children), 1 = internal, 2 = root (no outputs for parent)
// 64 nodes/block, 512 threads (8 waves). Wave w owns within-gate cols
// [16w, 16w+16). cf_buf: u32 per (node,col) = fh bf16 (lo) | c bf16 (hi).
template <int MODE>
__global__ __launch_bounds__(512, 2)
void tree_kernel(const float* __restrict__ embeds,
                 const u16* __restrict__ Wcat,
                 const u16* __restrict__ Wfxb,
                 const u16* __restrict__ Wfhb,
                 const float* __restrict__ bix, const float* __restrict__ bfx,
                 const float* __restrict__ box, const float* __restrict__ bux,
                 u16* __restrict__ hf, u32* __restrict__ cf_buf,
                 int n, int noff, int coff, int poff)
{
  constexpr bool HASC = (MODE >= 1);
  constexpr bool ROOT = (MODE == 2);
  extern __shared__ char smem[];
  u16* sx  = (u16*)smem;                    // 64 x 256B, swz bf16 (x, later h)
  u16* shs = (u16*)(smem + 16384);          // 64 x 256B, swz bf16 (hsum)

  const int tid  = threadIdx.x;
  const int wave = tid >> 6;                // 0..7
  const int lane = tid & 63;
  const int lg   = lane >> 4;
  const int ln   = lane & 15;
  const int pbase = blockIdx.x * 64;
  const int col  = wave * 16 + ln;

  // ---- stage x: thread t -> row t>>3, 16-float chunk t&7 ----
  {
    int row = tid >> 3;
    int k0  = (tid & 7) * 16;
    const float* src = embeds + (size_t)(noff + pbase + row) * HID + k0;
    unsigned sw = ((unsigned)(row & 7)) << 4;
    char* dst = (char*)sx + row * 256;
    float4 f0 = *(const float4*)src;
    float4 f1 = *(const float4*)(src + 4);
    float4 f2 = *(const float4*)(src + 8);
    float4 f3 = *(const float4*)(src + 12);
    *(short8*)(dst + (((unsigned)(k0 * 2)) ^ sw))      = f2bf8(f0, f1);
    *(short8*)(dst + (((unsigned)(k0 * 2 + 16)) ^ sw)) = f2bf8(f2, f3);
  }

  // ---- stage hsum (direct copy; produced by child level) ----
  if constexpr (HASC) {
    int row = tid >> 3, cg = tid & 7;
    const u16* src = hf + (size_t)(noff + pbase + row) * HID + cg * 16;
    short8 v0 = *(const short8*)src;
    short8 v1 = *(const short8*)(src + 8);
    unsigned sw = ((unsigned)(row & 7)) << 4;
    char* dst = (char*)shs + row * 256;
    *(short8*)(dst + ((cg * 32) ^ sw))      = v0;
    *(short8*)(dst + ((cg * 32 + 16) ^ sw)) = v1;
  }

  __syncthreads();

  // ---- fx GEMM + combine (fc) ----
  float fc[4][4];
  if constexpr (HASC) {
    floatx4 accx[4] = {};
#pragma unroll
    for (int kt = 0; kt < 4; ++kt) {
      short8 b = *(const short8*)(Wfxb + (size_t)(wave * 16 + ln) * HID + kt * 32 + lg * 8);
#pragma unroll
      for (int m = 0; m < 4; ++m) {
        int row = m * 16 + ln;
        unsigned sw = ((unsigned)(row & 7)) << 4;
        short8 a = *(const short8*)((char*)sx + row * 256 +
                                    (((unsigned)((kt * 32 + lg * 8) * 2)) ^ sw));
        accx[m] = __builtin_amdgcn_mfma_f32_16x16x32_bf16(a, b, accx[m], 0, 0, 0);
      }
    }
    // combine: batch-load 16 packed (fh,c) u32 per m-group, then gate math
    float bf = bfx[col];
#pragma unroll
    for (int m = 0; m < 4; ++m) {
      u32 cf[4][4];
#pragma unroll
      for (int r = 0; r < 4; ++r) {
        int row = m * 16 + lg * 4 + r;
        size_t cb = (size_t)(coff + 4 * (pbase + row)) * HID + col;
#pragma unroll
        for (int k = 0; k < 4; ++k)
          cf[r][k] = cf_buf[cb + (size_t)k * HID];
      }
#pragma unroll
      for (int r = 0; r < 4; ++r) {
        float fxv = accx[m][r] + bf;
        float s = 0.f;
#pragma unroll
        for (int k = 0; k < 4; ++k) {
          float fhv = bf2f((u16)(cf[r][k] & 0xFFFFu));
          float cv  = bf2f((u16)(cf[r][k] >> 16));
          s += sigm(fxv + fhv) * cv;
        }
        fc[m][r] = s;
      }
    }
  }

  // ---- main GEMM: [x | hsum] @ Wcat^T, K = 256 (internal/root) / 128 (leaf) ----
  floatx4 acc[4][3] = {};
  constexpr int KT = HASC ? 8 : 4;
#pragma unroll
  for (int kt = 0; kt < KT; ++kt) {
    short8 a[4];
#pragma unroll
    for (int m = 0; m < 4; ++m) {
      int row = m * 16 + ln;
      unsigned sw = ((unsigned)(row & 7)) << 4;
      const char* base = (kt < 4) ? (const char*)sx : (const char*)shs;
      int kb = ((kt & 3) * 32 + lg * 8) * 2;
      a[m] = *(const short8*)(base + row * 256 + (((unsigned)kb) ^ sw));
    }
#pragma unroll
    for (int g = 0; g < 3; ++g) {
      short8 b = *(const short8*)(Wcat + (size_t)((g * 8 + wave) * 16 + ln) * 256 + kt * 32 + lg * 8);
#pragma unroll
      for (int m = 0; m < 4; ++m)
        acc[m][g] = __builtin_amdgcn_mfma_f32_16x16x32_bf16(a[m], b, acc[m][g], 0, 0, 0);
    }
  }

  __syncthreads();   // sx reads done (h will overwrite it)

  // ---- epilogue: c,h; c kept in regs (bf16); h -> LDS; in-lane hsum ----
  u16 cbf[4][4];
  {
    float bi = bix[col], bo = box[col], bu = bux[col];
#pragma unroll
    for (int m = 0; m < 4; ++m) {
      float hs4 = 0.f;
#pragma unroll
      for (int r = 0; r < 4; ++r) {
        int row = m * 16 + lg * 4 + r;
        bool ok = ROOT ? (pbase + row < n) : true;
        if (ok) {
          float iv = sigm(acc[m][0][r] + bi);
          float ov = sigm(acc[m][1][r] + bo);
          float uv = tanh_fast(acc[m][2][r] + bu);
          float fcv = HASC ? fc[m][r] : 0.f;
          float cv = iv * uv + fcv;
          float hv = ov * tanh_fast(cv);
          if constexpr (ROOT) {
            hf[(size_t)(noff + pbase + row) * HID + col] = f2bf(hv);
          } else {
            cbf[m][r] = f2bf(cv);
            hs4 += hv;
            unsigned sw = ((unsigned)(row & 7)) << 4;
            *(u16*)((char*)sx + row * 256 + (((unsigned)(col * 2)) ^ sw)) = f2bf(hv);
          }
        }
      }
      if constexpr (!ROOT)
        hf[(size_t)(poff + (pbase >> 2) + m * 4 + lg) * HID + col] = f2bf(hs4);
    }
  }

  // ---- fh GEMM on LDS h tile; write packed (fh, c) u32 for parent ----
  if constexpr (!ROOT) {
    __syncthreads();   // all h writes to sx visible
    floatx4 ah[4] = {};
#pragma unroll
    for (int kt = 0; kt < 4; ++kt) {
      short8 b = *(const short8*)(Wfhb + (size_t)(wave * 16 + ln) * HID + kt * 32 + lg * 8);
#pragma unroll
      for (int m = 0; m < 4; ++m) {
        int row = m * 16 + ln;
        unsigned sw = ((unsigned)(row & 7)) << 4;
        short8 a = *(const short8*)((char*)sx + row * 256 +
                                    (((unsigned)((kt * 32 + lg * 8) * 2)) ^ sw));
        ah[m] = __builtin_amdgcn_mfma_f32_16x16x32_bf16(a, b, ah[m], 0, 0, 0);
      }
    }
#pragma unroll
    for (int m = 0; m < 4; ++m)
#pragma unroll
      for (int r = 0; r < 4; ++r) {
        int row = m * 16 + lg * 4 + r;
        u32 packed = ((u32)cbf[m][r] << 16) | (u32)f2bf(ah[m][r]);
        cf_buf[(size_t)(noff + pbase + row) * HID + col] = packed;
      }
  }
}

__global__ void out_kernel(const u16* __restrict__ hf, const float* __restrict__ Wout,
                           const float* __restrict__ bout, float* __restrict__ out)
{
  int t = threadIdx.x;
  if (t < 80) {                 // 16 roots x 5 labels
    int row = t / 5, lbl = t - row * 5;
    float s = bout[lbl];
    for (int k = 0; k < 128; ++k)
      s += bf2f(hf[row * 128 + k]) * Wout[lbl * 128 + k];
    out[t] = s;
  }
}

extern "C" void kernel_launch(void* const* d_in, const int* in_sizes, int n_in,
                              void* d_out, int out_size, void* d_ws, size_t ws_size,
                              hipStream_t stream)
{
  const float* embeds = (const float*)d_in[0];
  const float* Wix = (const float*)d_in[1];
  const float* bix = (const float*)d_in[2];
  const float* Wih = (const float*)d_in[3];
  const float* Wfx = (const float*)d_in[4];
  const float* bfx = (const float*)d_in[5];
  const float* Wfh = (const float*)d_in[6];
  const float* Wox = (const float*)d_in[7];
  const float* box = (const float*)d_in[8];
  const float* Woh = (const float*)d_in[9];
  const float* Wux = (const float*)d_in[10];
  const float* bux = (const float*)d_in[11];
  const float* Wuh = (const float*)d_in[12];
  const float* Wout = (const float*)d_in[13];
  const float* bout = (const float*)d_in[14];

  static const int counts[8]  = {16, 64, 256, 1024, 4096, 16384, 65536, 262144};
  static const int offsets[9] = {0, 16, 80, 336, 1360, 5456, 21840, 87376, 349520};

  char* ws = (char*)d_ws;
  u16* hf     = (u16*)ws;                                    // 89,477,120 B
  u32* cf_buf = (u32*)(ws + 89477120);                       // 178,954,240 B
  u16* Wcat   = (u16*)(ws + 89477120 + 178954240);           // 384*256*2
  u16* Wfxb   = Wcat + 384 * 256;
  u16* Wfhb   = Wfxb + 128 * 128;

  prep_weights<<<512, 256, 0, stream>>>(Wix, Wih, Wfx, Wfh, Wox, Woh, Wux, Wuh,
                                        Wcat, Wfxb, Wfhb);

  // level 7 (leaves): produces packed (fh,c) + hsum for level 6
  tree_kernel<0><<<262144 / 64, 512, 16384, stream>>>(
      embeds, Wcat, Wfxb, Wfhb, bix, bfx, box, bux,
      hf, cf_buf, 262144, 87376, 0, 21840);

  // levels 6..1 (internal)
  for (int l = 6; l >= 1; --l) {
    int n = counts[l];
    tree_kernel<1><<<n / 64, 512, 32768, stream>>>(
        embeds, Wcat, Wfxb, Wfhb, bix, bfx, box, bux,
        hf, cf_buf, n, offsets[l], offsets[l + 1], offsets[l - 1]);
  }

  // level 0 (roots): writes root h into hf slots 0..15
  tree_kernel<2><<<1, 512, 32768, stream>>>(
      embeds, Wcat, Wfxb, Wfhb, bix, bfx, box, bux,
      hf, cf_buf, 16, 0, 16, 0);

  out_kernel<<<1, 128, 0, stream>>>(hf, Wout, bout, (float*)d_out);
}